// Round 1
// baseline (359.211 us; speedup 1.0000x reference)
//
#include <hip/hip_runtime.h>
#include <hip/hip_bf16.h>

#define T 2048
#define HID 2048
#define NH 16
#define NKH 4
#define HD 128
#define GSZ 128

typedef __attribute__((ext_vector_type(8))) short short8;
typedef __attribute__((ext_vector_type(4))) float f32x4;

__device__ inline short f2b(float f) {
    unsigned int u = __float_as_uint(f);
    unsigned int r = (u + 0x7fffu + ((u >> 16) & 1u)) >> 16;
    return (short)r;
}

// ---------------- dequant: int4 GPTQ -> bf16 W^T [N][K] ----------------
__global__ __launch_bounds__(256) void dequant_kernel(
    const int* __restrict__ qw, const float* __restrict__ sc,
    const int* __restrict__ qz, short* __restrict__ Wt, int K, int N) {
    int tid = blockIdx.x * blockDim.x + threadIdx.x;
    int K8 = K >> 3;
    if (tid >= N * K8) return;
    int n = tid / K8;
    int k8 = tid - n * K8;
    int q32 = qw[k8 * N + n];
    int g = (k8 << 3) / GSZ;
    float scale = sc[g * N + n];
    int z = (qz[g * (N >> 3) + (n >> 3)] >> ((n & 7) * 4)) & 15;
    float zf = (float)(z + 1);
    short8 out;
#pragma unroll
    for (int kk = 0; kk < 8; kk++) {
        int q = (q32 >> (kk * 4)) & 15;
        out[kk] = f2b(scale * ((float)q - zf));
    }
    *reinterpret_cast<short8*>(&Wt[n * K + (k8 << 3)]) = out;
}

// ---------------- cast x f32 -> bf16 ----------------
__global__ __launch_bounds__(256) void cast_kernel(
    const float* __restrict__ x, short* __restrict__ xb, int n8) {
    int i = blockIdx.x * blockDim.x + threadIdx.x;
    if (i >= n8) return;
    const float4* xp = reinterpret_cast<const float4*>(x) + i * 2;
    float4 a = xp[0], b = xp[1];
    short8 o;
    o[0] = f2b(a.x); o[1] = f2b(a.y); o[2] = f2b(a.z); o[3] = f2b(a.w);
    o[4] = f2b(b.x); o[5] = f2b(b.y); o[6] = f2b(b.z); o[7] = f2b(b.w);
    reinterpret_cast<short8*>(xb)[i] = o;
}

// ---------------- GEMM: C[M,N] f32 = A[M,K]bf16 * Bt[N,K]bf16^T ----------------
#define BM 128
#define BN 128
#define BK 64
#define LDT (BK + 24)  // 88 elems -> 176B row stride (16B aligned, ~2-way banks)

__global__ __launch_bounds__(256) void gemm_bt(
    const short* __restrict__ A, const short* __restrict__ Bt,
    float* __restrict__ C, int M, int N, int K) {
    __shared__ short As[BM * LDT];
    __shared__ short Bs[BN * LDT];
    const int t = threadIdx.x;
    const int lane = t & 63;
    const int w = t >> 6;
    const int bm = blockIdx.y * BM;
    const int bn = blockIdx.x * BN;
    const int wm = (w >> 1) * 64;
    const int wn = (w & 1) * 64;
    const int lr = lane & 15;
    const int lk = (lane >> 4) * 8;
    f32x4 acc[4][4] = {};
    for (int k0 = 0; k0 < K; k0 += BK) {
        __syncthreads();
#pragma unroll
        for (int i = 0; i < 4; i++) {
            int id = i * 256 + t;
            int row = id >> 3;
            int col = (id & 7) << 3;
            *reinterpret_cast<short8*>(&As[row * LDT + col]) =
                *reinterpret_cast<const short8*>(&A[(bm + row) * K + k0 + col]);
            *reinterpret_cast<short8*>(&Bs[row * LDT + col]) =
                *reinterpret_cast<const short8*>(&Bt[(bn + row) * K + k0 + col]);
        }
        __syncthreads();
#pragma unroll
        for (int kc = 0; kc < 2; kc++) {
            short8 af[4], bf[4];
#pragma unroll
            for (int m = 0; m < 4; m++)
                af[m] = *reinterpret_cast<const short8*>(
                    &As[(wm + m * 16 + lr) * LDT + kc * 32 + lk]);
#pragma unroll
            for (int n = 0; n < 4; n++)
                bf[n] = *reinterpret_cast<const short8*>(
                    &Bs[(wn + n * 16 + lr) * LDT + kc * 32 + lk]);
#pragma unroll
            for (int m = 0; m < 4; m++)
#pragma unroll
                for (int n = 0; n < 4; n++)
                    acc[m][n] = __builtin_amdgcn_mfma_f32_16x16x32_bf16(
                        af[m], bf[n], acc[m][n], 0, 0, 0);
        }
    }
    const int rowb = bm + wm + (lane >> 4) * 4;
    const int colb = bn + wn + lr;
#pragma unroll
    for (int m = 0; m < 4; m++)
#pragma unroll
        for (int n = 0; n < 4; n++)
#pragma unroll
            for (int rr = 0; rr < 4; rr++)
                C[(rowb + m * 16 + rr) * N + colb + n * 16] = acc[m][n][rr];
}

// ---------------- rmsnorm + rope ----------------
__global__ __launch_bounds__(128) void normrope_kernel(
    const float* __restrict__ qkv, const float* __restrict__ qw,
    const float* __restrict__ kw, const int* __restrict__ pos,
    short* __restrict__ Qb, short* __restrict__ Kb) {
    int tt = blockIdx.x;
    int hh = blockIdx.y;
    int d = threadIdx.x;
    bool isq = hh < NH;
    int h = isq ? hh : hh - NH;
    int off = isq ? h * HD : HID + h * HD;
    float x = qkv[tt * 3072 + off + d];
    float ss = x * x;
#pragma unroll
    for (int mask = 1; mask < 64; mask <<= 1) ss += __shfl_xor(ss, mask, 64);
    __shared__ float red[2];
    __shared__ float vals[HD];
    if ((d & 63) == 0) red[d >> 6] = ss;
    __syncthreads();
    float tot = red[0] + red[1];
    float r = rsqrtf(tot * (1.0f / HD) + 1e-6f);
    float wv = isq ? qw[d] : kw[d];
    float xn = x * r * wv;
    vals[d] = xn;
    __syncthreads();
    int p = pos[tt];
    int i = d & 63;
    float inv = exp2f(-(float)i * (13.287712379549449f / 64.0f));
    float ang = (float)p * inv;
    float c, s;
    sincosf(ang, &s, &c);
    float other = vals[d ^ 64];
    float out = (d < 64) ? (xn * c - other * s) : (xn * c + other * s);
    if (isq) Qb[tt * HID + h * HD + d] = f2b(out);
    else     Kb[(h * T + tt) * HD + d] = f2b(out);
}

// ---------------- V transpose: qkv f32 -> Vt[KH][HD][T] bf16 ----------------
__global__ __launch_bounds__(256) void vtrans_kernel(
    const float* __restrict__ qkv, short* __restrict__ Vt) {
    __shared__ float tile[32][33];
    int h = blockIdx.z;
    int d0 = blockIdx.y * 32;
    int t0 = blockIdx.x * 32;
    int tx = threadIdx.x & 31;
    int ty = threadIdx.x >> 5;
#pragma unroll
    for (int i = 0; i < 32; i += 8)
        tile[ty + i][tx] = qkv[(t0 + ty + i) * 3072 + 2560 + h * HD + d0 + tx];
    __syncthreads();
#pragma unroll
    for (int i = 0; i < 32; i += 8)
        Vt[(h * HD + d0 + ty + i) * T + t0 + tx] = f2b(tile[tx][ty + i]);
}

// ---------------- flash attention, 1 wave / 16 q-rows ----------------
__global__ __launch_bounds__(64) void attn_kernel(
    const short* __restrict__ Qb, const short* __restrict__ Kb,
    const short* __restrict__ Vt, short* __restrict__ O) {
    __shared__ short P[16 * 48];
    const int l = threadIdx.x;
    const int h = blockIdx.y;
    const int kvh = h >> 2;
    const int qt0 = blockIdx.x * 16;
    const int lr = l & 15;
    const int lk = (l >> 4) * 8;
    short8 qf[4];
    {
        const short* qp = Qb + (qt0 + lr) * HID + h * HD + lk;
#pragma unroll
        for (int kk = 0; kk < 4; kk++)
            qf[kk] = *reinterpret_cast<const short8*>(qp + kk * 32);
    }
    f32x4 oacc[8] = {};
    float m[4], lsum[4];
#pragma unroll
    for (int rr = 0; rr < 4; rr++) { m[rr] = -INFINITY; lsum[rr] = 0.f; }
    const float scale = 0.08838834764831845f;  // 1/sqrt(128)
    const int nt = (qt0 + 47) >> 5;
    const int rowb = qt0 + (l >> 4) * 4;
    for (int j = 0; j < nt; j++) {
        const int key0 = j * 32;
        f32x4 s0 = {0.f, 0.f, 0.f, 0.f}, s1 = {0.f, 0.f, 0.f, 0.f};
        const short* kp = Kb + ((kvh * T + key0 + lr) * HD) + lk;
#pragma unroll
        for (int kk = 0; kk < 4; kk++) {
            short8 b0 = *reinterpret_cast<const short8*>(kp + kk * 32);
            short8 b1 = *reinterpret_cast<const short8*>(kp + 16 * HD + kk * 32);
            s0 = __builtin_amdgcn_mfma_f32_16x16x32_bf16(qf[kk], b0, s0, 0, 0, 0);
            s1 = __builtin_amdgcn_mfma_f32_16x16x32_bf16(qf[kk], b1, s1, 0, 0, 0);
        }
        float p0[4], p1[4], pm[4];
#pragma unroll
        for (int rr = 0; rr < 4; rr++) {
            int row = rowb + rr;
            float v0 = (key0 + lr <= row) ? s0[rr] * scale : -1e30f;
            float v1 = (key0 + 16 + lr <= row) ? s1[rr] * scale : -1e30f;
            p0[rr] = v0; p1[rr] = v1;
            pm[rr] = fmaxf(v0, v1);
        }
#pragma unroll
        for (int mask = 1; mask < 16; mask <<= 1)
#pragma unroll
            for (int rr = 0; rr < 4; rr++)
                pm[rr] = fmaxf(pm[rr], __shfl_xor(pm[rr], mask, 64));
        float alpha[4], ps[4];
#pragma unroll
        for (int rr = 0; rr < 4; rr++) {
            float mn = fmaxf(m[rr], pm[rr]);
            alpha[rr] = __expf(m[rr] - mn);
            m[rr] = mn;
            p0[rr] = __expf(p0[rr] - mn);
            p1[rr] = __expf(p1[rr] - mn);
            ps[rr] = p0[rr] + p1[rr];
        }
#pragma unroll
        for (int mask = 1; mask < 16; mask <<= 1)
#pragma unroll
            for (int rr = 0; rr < 4; rr++)
                ps[rr] += __shfl_xor(ps[rr], mask, 64);
#pragma unroll
        for (int rr = 0; rr < 4; rr++) {
            lsum[rr] = lsum[rr] * alpha[rr] + ps[rr];
#pragma unroll
            for (int c = 0; c < 8; c++) oacc[c][rr] *= alpha[rr];
        }
#pragma unroll
        for (int rr = 0; rr < 4; rr++) {
            int prow = (l >> 4) * 4 + rr;
            P[prow * 48 + lr] = f2b(p0[rr]);
            P[prow * 48 + 16 + lr] = f2b(p1[rr]);
        }
        __syncthreads();
        short8 pa = *reinterpret_cast<const short8*>(&P[lr * 48 + lk]);
        __syncthreads();
        const short* vp = Vt + (kvh * HD) * T + key0;
#pragma unroll
        for (int c = 0; c < 8; c++) {
            short8 bv = *reinterpret_cast<const short8*>(vp + (c * 16 + lr) * T + lk);
            oacc[c] = __builtin_amdgcn_mfma_f32_16x16x32_bf16(pa, bv, oacc[c], 0, 0, 0);
        }
    }
    float linv[4];
#pragma unroll
    for (int rr = 0; rr < 4; rr++) linv[rr] = 1.0f / lsum[rr];
#pragma unroll
    for (int c = 0; c < 8; c++)
#pragma unroll
        for (int rr = 0; rr < 4; rr++)
            O[(rowb + rr) * HID + h * HD + c * 16 + lr] = f2b(oacc[c][rr] * linv[rr]);
}

extern "C" void kernel_launch(void* const* d_in, const int* in_sizes, int n_in,
                              void* d_out, int out_size, void* d_ws, size_t ws_size,
                              hipStream_t stream) {
    const float* x = (const float*)d_in[0];
    const int* positions = (const int*)d_in[1];
    const int* qw_q = (const int*)d_in[2];
    const float* sc_q = (const float*)d_in[3];
    const int* qz_q = (const int*)d_in[4];
    const int* qw_k = (const int*)d_in[5];
    const float* sc_k = (const float*)d_in[6];
    const int* qz_k = (const int*)d_in[7];
    const int* qw_v = (const int*)d_in[8];
    const float* sc_v = (const float*)d_in[9];
    const int* qz_v = (const int*)d_in[10];
    const int* qw_o = (const int*)d_in[11];
    const float* sc_o = (const float*)d_in[12];
    const int* qz_o = (const int*)d_in[13];
    const float* qnw = (const float*)d_in[14];
    const float* knw = (const float*)d_in[15];
    float* out = (float*)d_out;

    char* ws = (char*)d_ws;
    short* Wqkv = (short*)(ws);                  // [3072][2048] bf16 (q rows 0-2047, k 2048-2559, v 2560-3071)
    short* Wo   = (short*)(ws + 12582912);       // [2048][2048] bf16
    short* xb   = (short*)(ws + 20971520);       // [2048][2048] bf16
    float* qkv  = (float*)(ws + 29360128);       // [2048][3072] f32
    short* Qb   = (short*)(ws + 54525952);       // [2048][2048] bf16
    short* Kb   = (short*)(ws + 62914560);       // [4][2048][128] bf16
    short* Vt   = (short*)(ws + 65011712);       // [4][128][2048] bf16
    short* Ob   = (short*)(ws + 67108864);       // [2048][2048] bf16

    // dequant (transposed bf16 weights)
    dequant_kernel<<<(2048 * 256 + 255) / 256, 256, 0, stream>>>(qw_q, sc_q, qz_q, Wqkv, 2048, 2048);
    dequant_kernel<<<(512 * 256 + 255) / 256, 256, 0, stream>>>(qw_k, sc_k, qz_k, Wqkv + 2048 * 2048, 2048, 512);
    dequant_kernel<<<(512 * 256 + 255) / 256, 256, 0, stream>>>(qw_v, sc_v, qz_v, Wqkv + 2560 * 2048, 2048, 512);
    dequant_kernel<<<(2048 * 256 + 255) / 256, 256, 0, stream>>>(qw_o, sc_o, qz_o, Wo, 2048, 2048);

    cast_kernel<<<(524288 + 255) / 256, 256, 0, stream>>>(x, xb, 524288);

    dim3 g1(3072 / BN, 2048 / BM);
    gemm_bt<<<g1, 256, 0, stream>>>(xb, Wqkv, qkv, 2048, 3072, 2048);

    dim3 g2(T, NH + NKH);
    normrope_kernel<<<g2, 128, 0, stream>>>(qkv, qnw, knw, positions, Qb, Kb);

    dim3 g3(T / 32, HD / 32, NKH);
    vtrans_kernel<<<g3, 256, 0, stream>>>(qkv, Vt);

    dim3 g4(T / 16, NH);
    attn_kernel<<<g4, 64, 0, stream>>>(Qb, Kb, Vt, Ob);

    dim3 g5(2048 / BN, 2048 / BM);
    gemm_bt<<<g5, 256, 0, stream>>>(Ob, Wo, out, 2048, 2048, 2048);
}

// Round 2
// 270.910 us; speedup vs baseline: 1.3259x; 1.3259x over previous
//
#include <hip/hip_runtime.h>
#include <hip/hip_bf16.h>

#define T 2048
#define HID 2048
#define NH 16
#define NKH 4
#define HD 128
#define GSZ 128

typedef __attribute__((ext_vector_type(8))) short short8;
typedef __attribute__((ext_vector_type(4))) float f32x4;

#define GLOAD16(gp, lp) __builtin_amdgcn_global_load_lds( \
    (const __attribute__((address_space(1))) void*)(gp), \
    (__attribute__((address_space(3))) void*)(lp), 16, 0, 0)

__device__ inline short f2b(float f) {
    unsigned int u = __float_as_uint(f);
    unsigned int r = (u + 0x7fffu + ((u >> 16) & 1u)) >> 16;
    return (short)r;
}

// ---------------- dequant: int4 GPTQ -> bf16 W^T [N][K] ----------------
__global__ __launch_bounds__(256) void dequant_kernel(
    const int* __restrict__ qw, const float* __restrict__ sc,
    const int* __restrict__ qz, short* __restrict__ Wt, int K, int N) {
    int tid = blockIdx.x * blockDim.x + threadIdx.x;
    int K8 = K >> 3;
    if (tid >= N * K8) return;
    int n = tid / K8;
    int k8 = tid - n * K8;
    int q32 = qw[k8 * N + n];
    int g = (k8 << 3) / GSZ;
    float scale = sc[g * N + n];
    int z = (qz[g * (N >> 3) + (n >> 3)] >> ((n & 7) * 4)) & 15;
    float zf = (float)(z + 1);
    short8 out;
#pragma unroll
    for (int kk = 0; kk < 8; kk++) {
        int q = (q32 >> (kk * 4)) & 15;
        out[kk] = f2b(scale * ((float)q - zf));
    }
    *reinterpret_cast<short8*>(&Wt[n * K + (k8 << 3)]) = out;
}

// ---------------- cast x f32 -> bf16 ----------------
__global__ __launch_bounds__(256) void cast_kernel(
    const float* __restrict__ x, short* __restrict__ xb, int n8) {
    int i = blockIdx.x * blockDim.x + threadIdx.x;
    if (i >= n8) return;
    const float4* xp = reinterpret_cast<const float4*>(x) + i * 2;
    float4 a = xp[0], b = xp[1];
    short8 o;
    o[0] = f2b(a.x); o[1] = f2b(a.y); o[2] = f2b(a.z); o[3] = f2b(a.w);
    o[4] = f2b(b.x); o[5] = f2b(b.y); o[6] = f2b(b.z); o[7] = f2b(b.w);
    reinterpret_cast<short8*>(xb)[i] = o;
}

// ---------------- GEMM (m97 structure): C f32 = A bf16 * Bt bf16^T ----------------
#define BM 128
#define BN 128
#define BK 64

__global__ __launch_bounds__(256) void gemm_bt(
    const short* __restrict__ A, const short* __restrict__ Bt,
    float* __restrict__ C, int M, int N, int K) {
    __shared__ short As[BM * BK];
    __shared__ short Bs[BN * BK];
    const int t = threadIdx.x;
    const int lane = t & 63;
    const int w = t >> 6;
    const int bm = blockIdx.y * BM;
    const int bn = blockIdx.x * BN;
    const int wm = (w >> 1) * 64;
    const int wn = (w & 1) * 64;
    const int lr = lane & 15;
    const int lk = (lane >> 4) * 8;
    f32x4 acc[4][4] = {};
    for (int k0 = 0; k0 < K; k0 += BK) {
        __syncthreads();
#pragma unroll
        for (int i = 0; i < 4; i++) {
            int c = w * 4 + i;
            int grow = c * 8 + (lane >> 3);
            int gcol = (lane & 7) * 8;
            GLOAD16(&A[(bm + grow) * K + k0 + gcol], &As[c * 512]);
            GLOAD16(&Bt[(bn + grow) * K + k0 + gcol], &Bs[c * 512]);
        }
        __syncthreads();
#pragma unroll
        for (int kc = 0; kc < 2; kc++) {
            short8 af[4], bf[4];
#pragma unroll
            for (int m = 0; m < 4; m++)
                af[m] = *reinterpret_cast<const short8*>(
                    &As[(wm + m * 16 + lr) * BK + kc * 32 + lk]);
#pragma unroll
            for (int n = 0; n < 4; n++)
                bf[n] = *reinterpret_cast<const short8*>(
                    &Bs[(wn + n * 16 + lr) * BK + kc * 32 + lk]);
#pragma unroll
            for (int m = 0; m < 4; m++)
#pragma unroll
                for (int n = 0; n < 4; n++)
                    acc[m][n] = __builtin_amdgcn_mfma_f32_16x16x32_bf16(
                        af[m], bf[n], acc[m][n], 0, 0, 0);
        }
    }
    const int rowb = bm + wm + (lane >> 4) * 4;
    const int colb = bn + wn + lr;
#pragma unroll
    for (int m = 0; m < 4; m++)
#pragma unroll
        for (int n = 0; n < 4; n++)
#pragma unroll
            for (int rr = 0; rr < 4; rr++)
                C[(rowb + m * 16 + rr) * N + colb + n * 16] = acc[m][n][rr];
}

// ---------------- rmsnorm + rope ----------------
__global__ __launch_bounds__(128) void normrope_kernel(
    const float* __restrict__ qkv, const float* __restrict__ qw,
    const float* __restrict__ kw, const int* __restrict__ pos,
    short* __restrict__ Qb, short* __restrict__ Kb) {
    int tt = blockIdx.x;
    int hh = blockIdx.y;
    int d = threadIdx.x;
    bool isq = hh < NH;
    int h = isq ? hh : hh - NH;
    int off = isq ? h * HD : HID + h * HD;
    float x = qkv[tt * 3072 + off + d];
    float ss = x * x;
#pragma unroll
    for (int mask = 1; mask < 64; mask <<= 1) ss += __shfl_xor(ss, mask, 64);
    __shared__ float red[2];
    __shared__ float vals[HD];
    if ((d & 63) == 0) red[d >> 6] = ss;
    __syncthreads();
    float tot = red[0] + red[1];
    float r = rsqrtf(tot * (1.0f / HD) + 1e-6f);
    float wv = isq ? qw[d] : kw[d];
    float xn = x * r * wv;
    vals[d] = xn;
    __syncthreads();
    int p = pos[tt];
    int i = d & 63;
    float inv = exp2f(-(float)i * (13.287712379549449f / 64.0f));
    float ang = (float)p * inv;
    float c, s;
    sincosf(ang, &s, &c);
    float other = vals[d ^ 64];
    float out = (d < 64) ? (xn * c - other * s) : (xn * c + other * s);
    if (isq) Qb[tt * HID + h * HD + d] = f2b(out);
    else     Kb[(h * T + tt) * HD + d] = f2b(out);
}

// ---------------- V transpose: qkv f32 -> Vt[KH][HD][T] bf16 ----------------
__global__ __launch_bounds__(256) void vtrans_kernel(
    const float* __restrict__ qkv, short* __restrict__ Vt) {
    __shared__ float tile[32][33];
    int h = blockIdx.z;
    int d0 = blockIdx.y * 32;
    int t0 = blockIdx.x * 32;
    int tx = threadIdx.x & 31;
    int ty = threadIdx.x >> 5;
#pragma unroll
    for (int i = 0; i < 32; i += 8)
        tile[ty + i][tx] = qkv[(t0 + ty + i) * 3072 + 2560 + h * HD + d0 + tx];
    __syncthreads();
#pragma unroll
    for (int i = 0; i < 32; i += 8)
        Vt[(h * HD + d0 + ty + i) * T + t0 + tx] = f2b(tile[tx][ty + i]);
}

// ---------------- flash attention: 4 waves, QBLK=64, KVBLK=64, LDS dbuf ----------------
#define QB 64
#define KVB 64

__global__ __launch_bounds__(256) void attn_kernel(
    const short* __restrict__ Qb, const short* __restrict__ Kb,
    const short* __restrict__ Vt, short* __restrict__ O) {
    __shared__ short Ks[2][KVB * HD];     // [64][128] linear
    __shared__ short Vs[2][HD * KVB];     // [128][64] linear
    __shared__ short P[4][16 * 72];
    const int t = threadIdx.x;
    const int lane = t & 63;
    const int w = t >> 6;
    const int h = blockIdx.y;
    const int kvh = h >> 2;
    int bx = blockIdx.x;
    const int qt = (bx & 1) ? ((int)gridDim.x - 1 - (bx >> 1)) : (bx >> 1);
    const int qb0 = qt * QB;
    const int lr = lane & 15;
    const int lk = (lane >> 4) * 8;
    const int rowb = qb0 + w * 16 + (lane >> 4) * 4;

    short8 qf[4];
    {
        const short* qp = Qb + (qb0 + w * 16 + lr) * HID + h * HD + lk;
#pragma unroll
        for (int kk = 0; kk < 4; kk++)
            qf[kk] = *reinterpret_cast<const short8*>(qp + kk * 32);
    }
    f32x4 oacc[8] = {};
    float m[4], lsum[4];
#pragma unroll
    for (int rr = 0; rr < 4; rr++) { m[rr] = -INFINITY; lsum[rr] = 0.f; }
    const float scale = 0.08838834764831845f;  // 1/sqrt(128)
    const int nt = qt + 1;

    const short* kgb = Kb + (kvh * T) * HD;
    const short* vgb = Vt + (kvh * HD) * T;
    const int krow = (lane >> 4);           // + c2*4
    const int kcol = (lane & 15) * 8;
    const int vrow = (lane >> 3);           // + c2*8
    const int vcol = (lane & 7) * 8;

    // prologue: stage tile 0 into buf 0
#pragma unroll
    for (int i = 0; i < 4; i++) {
        int c2 = w * 4 + i;
        GLOAD16(kgb + (c2 * 4 + krow) * HD + kcol, &Ks[0][c2 * 512]);
        GLOAD16(vgb + (c2 * 8 + vrow) * T + vcol, &Vs[0][c2 * 512]);
    }
    __syncthreads();

    int cur = 0;
    for (int j = 0; j < nt; j++) {
        const int key0 = j * KVB;
        if (j + 1 < nt) {
            const int nk0 = key0 + KVB;
#pragma unroll
            for (int i = 0; i < 4; i++) {
                int c2 = w * 4 + i;
                GLOAD16(kgb + (nk0 + c2 * 4 + krow) * HD + kcol, &Ks[cur ^ 1][c2 * 512]);
                GLOAD16(vgb + (c2 * 8 + vrow) * T + nk0 + vcol, &Vs[cur ^ 1][c2 * 512]);
            }
        }
        // ---- QK^T: S[16q][64k] per wave ----
        f32x4 s[4] = {};
        __builtin_amdgcn_s_setprio(1);
#pragma unroll
        for (int kt = 0; kt < 4; kt++) {
#pragma unroll
            for (int kk = 0; kk < 4; kk++) {
                short8 b = *reinterpret_cast<const short8*>(
                    &Ks[cur][(kt * 16 + lr) * HD + kk * 32 + lk]);
                s[kt] = __builtin_amdgcn_mfma_f32_16x16x32_bf16(qf[kk], b, s[kt], 0, 0, 0);
            }
        }
        __builtin_amdgcn_s_setprio(0);
        // ---- softmax ----
        float p[4][4], pm[4];
#pragma unroll
        for (int rr = 0; rr < 4; rr++) {
            int row = rowb + rr;
            pm[rr] = -INFINITY;
#pragma unroll
            for (int kt = 0; kt < 4; kt++) {
                float v = (key0 + kt * 16 + lr <= row) ? s[kt][rr] * scale : -1e30f;
                p[kt][rr] = v;
                pm[rr] = fmaxf(pm[rr], v);
            }
        }
#pragma unroll
        for (int mask = 1; mask < 16; mask <<= 1)
#pragma unroll
            for (int rr = 0; rr < 4; rr++)
                pm[rr] = fmaxf(pm[rr], __shfl_xor(pm[rr], mask, 64));
        float alpha[4], ps[4];
#pragma unroll
        for (int rr = 0; rr < 4; rr++) {
            float mn = fmaxf(m[rr], pm[rr]);
            alpha[rr] = __expf(m[rr] - mn);
            m[rr] = mn;
            ps[rr] = 0.f;
#pragma unroll
            for (int kt = 0; kt < 4; kt++) {
                p[kt][rr] = __expf(p[kt][rr] - mn);
                ps[rr] += p[kt][rr];
            }
        }
#pragma unroll
        for (int mask = 1; mask < 16; mask <<= 1)
#pragma unroll
            for (int rr = 0; rr < 4; rr++)
                ps[rr] += __shfl_xor(ps[rr], mask, 64);
#pragma unroll
        for (int rr = 0; rr < 4; rr++) {
            lsum[rr] = lsum[rr] * alpha[rr] + ps[rr];
#pragma unroll
            for (int c = 0; c < 8; c++) oacc[c][rr] *= alpha[rr];
        }
        {
            int prow = (lane >> 4) * 4;
#pragma unroll
            for (int rr = 0; rr < 4; rr++)
#pragma unroll
                for (int kt = 0; kt < 4; kt++)
                    P[w][(prow + rr) * 72 + kt * 16 + lr] = f2b(p[kt][rr]);
        }
        __syncthreads();   // P visible wave-local; also drains staging vmcnt
        // ---- PV: O[16q][128d] += P[16][64] * V[64][128] ----
        short8 pa[2];
#pragma unroll
        for (int kc = 0; kc < 2; kc++)
            pa[kc] = *reinterpret_cast<const short8*>(&P[w][lr * 72 + kc * 32 + lk]);
        __builtin_amdgcn_s_setprio(1);
#pragma unroll
        for (int c = 0; c < 8; c++) {
#pragma unroll
            for (int kc = 0; kc < 2; kc++) {
                short8 bv = *reinterpret_cast<const short8*>(
                    &Vs[cur][(c * 16 + lr) * KVB + kc * 32 + lk]);
                oacc[c] = __builtin_amdgcn_mfma_f32_16x16x32_bf16(pa[kc], bv, oacc[c], 0, 0, 0);
            }
        }
        __builtin_amdgcn_s_setprio(0);
        __syncthreads();   // all waves done with buf cur before it's restaged
        cur ^= 1;
    }
    float linv[4];
#pragma unroll
    for (int rr = 0; rr < 4; rr++) linv[rr] = 1.0f / lsum[rr];
#pragma unroll
    for (int c = 0; c < 8; c++)
#pragma unroll
        for (int rr = 0; rr < 4; rr++)
            O[(rowb + rr) * HID + h * HD + c * 16 + lr] = f2b(oacc[c][rr] * linv[rr]);
}

extern "C" void kernel_launch(void* const* d_in, const int* in_sizes, int n_in,
                              void* d_out, int out_size, void* d_ws, size_t ws_size,
                              hipStream_t stream) {
    const float* x = (const float*)d_in[0];
    const int* positions = (const int*)d_in[1];
    const int* qw_q = (const int*)d_in[2];
    const float* sc_q = (const float*)d_in[3];
    const int* qz_q = (const int*)d_in[4];
    const int* qw_k = (const int*)d_in[5];
    const float* sc_k = (const float*)d_in[6];
    const int* qz_k = (const int*)d_in[7];
    const int* qw_v = (const int*)d_in[8];
    const float* sc_v = (const float*)d_in[9];
    const int* qz_v = (const int*)d_in[10];
    const int* qw_o = (const int*)d_in[11];
    const float* sc_o = (const float*)d_in[12];
    const int* qz_o = (const int*)d_in[13];
    const float* qnw = (const float*)d_in[14];
    const float* knw = (const float*)d_in[15];
    float* out = (float*)d_out;

    char* ws = (char*)d_ws;
    short* Wqkv = (short*)(ws);                  // [3072][2048] bf16
    short* Wo   = (short*)(ws + 12582912);       // [2048][2048] bf16
    short* xb   = (short*)(ws + 20971520);       // [2048][2048] bf16
    float* qkv  = (float*)(ws + 29360128);       // [2048][3072] f32
    short* Qb   = (short*)(ws + 54525952);       // [2048][2048] bf16
    short* Kb   = (short*)(ws + 62914560);       // [4][2048][128] bf16
    short* Vt   = (short*)(ws + 65011712);       // [4][128][2048] bf16
    short* Ob   = (short*)(ws + 67108864);       // [2048][2048] bf16

    dequant_kernel<<<(2048 * 256 + 255) / 256, 256, 0, stream>>>(qw_q, sc_q, qz_q, Wqkv, 2048, 2048);
    dequant_kernel<<<(512 * 256 + 255) / 256, 256, 0, stream>>>(qw_k, sc_k, qz_k, Wqkv + 2048 * 2048, 2048, 512);
    dequant_kernel<<<(512 * 256 + 255) / 256, 256, 0, stream>>>(qw_v, sc_v, qz_v, Wqkv + 2560 * 2048, 2048, 512);
    dequant_kernel<<<(2048 * 256 + 255) / 256, 256, 0, stream>>>(qw_o, sc_o, qz_o, Wo, 2048, 2048);

    cast_kernel<<<(524288 + 255) / 256, 256, 0, stream>>>(x, xb, 524288);

    dim3 g1(3072 / BN, 2048 / BM);
    gemm_bt<<<g1, 256, 0, stream>>>(xb, Wqkv, qkv, 2048, 3072, 2048);

    dim3 g2(T, NH + NKH);
    normrope_kernel<<<g2, 128, 0, stream>>>(qkv, qnw, knw, positions, Qb, Kb);

    dim3 g3(T / 32, HD / 32, NKH);
    vtrans_kernel<<<g3, 256, 0, stream>>>(qkv, Vt);

    dim3 g4(T / QB, NH);
    attn_kernel<<<g4, 256, 0, stream>>>(Qb, Kb, Vt, Ob);

    dim3 g5(2048 / BN, 2048 / BM);
    gemm_bt<<<g5, 256, 0, stream>>>(Ob, Wo, out, 2048, 2048, 2048);
}